// Round 18
// baseline (127.021 us; speedup 1.0000x reference)
//
#include <hip/hip_runtime.h>
#include <stdint.h>

#define NPRIOR 8400
#define NB 32
#define NCLS 80
#define KTOP 1000
#define CAP 8400   // worst-case candidates
#define CPAD 16    // ints per counter slot (64B)
#define PCH 8      // class chunks
#define CPC 10     // classes per chunk

typedef unsigned long long u64;

// Bit-exact replica of numpy's float32 SIMD exp (Cephes-style, FMA path).
__device__ __forceinline__ float exp_np(float x) {
#pragma clang fp contract(off)
    if (x > 88.72283935546875f) return __builtin_huge_valf();
    if (x < -87.3365478515625f) return 0.0f;
    float q = rintf(x * 1.442695040f);
    float r = fmaf(q, -6.93145752e-1f, x);
    r = fmaf(q, -1.42860677e-6f, r);
    float p = fmaf(1.9875691500e-4f, r, 1.3981999507e-3f);
    p = fmaf(p, r, 8.3334519073e-3f);
    p = fmaf(p, r, 4.1665795894e-2f);
    p = fmaf(p, r, 1.6666665459e-1f);
    p = fmaf(p, r, 5.0000001201e-1f);
    float r2 = r * r;
    p = fmaf(p, r2, r);
    p = p + 1.0f;
    return ldexpf(p, (int)q);
}
__device__ __forceinline__ float sigm_np(float x) {
#pragma clang fp contract(off)
    float t = exp_np(-x);
    return 1.0f / (1.0f + t);
}

__device__ __forceinline__ void level_of(int n, int& W, int& s, int& loc) {
    if (n < 6400)      { W = 80; s = 8;  loc = n; }
    else if (n < 8000) { W = 40; s = 16; loc = n - 6400; }
    else               { W = 20; s = 32; loc = n - 8000; }
}

__device__ float4 decode32(int b, int n,
                           const float* bb0, const float* bb1, const float* bb2) {
#pragma clang fp contract(off)
    int W, s, loc; level_of(n, W, s, loc);
    const float* bb = (s == 8) ? bb0 : (s == 16) ? bb1 : bb2;
    int hw = W * W;
    int y = loc / W, x = loc - y * W;
    const float* bp = bb + (size_t)b * 4 * hw + y * W + x;
    float fs = (float)s;
    float cx = (float)x * fs, cy = (float)y * fs;
    float xc = bp[0] * fs + cx;
    float yc = bp[hw] * fs + cy;
    float wv = exp_np(bp[2 * hw]) * fs;
    float hv = exp_np(bp[3 * hw]) * fs;
    float wv2 = wv * 0.5f, hv2 = hv * 0.5f;
    float4 r;
    r.x = xc - wv2;
    r.y = yc - hv2;
    r.z = xc + wv2;
    r.w = yc + hv2;
    return r;
}

__device__ __forceinline__ unsigned flt2ord(float f) {
    unsigned u = __float_as_uint(f);
    return u ^ ((u >> 31) ? 0xffffffffu : 0x80000000u);
}
__device__ __forceinline__ float ord2flt(unsigned u) {
    u ^= ((u >> 31) ? 0x80000000u : 0xffffffffu);
    return __uint_as_float(u);
}
__device__ __forceinline__ u64 packlc(float l, int c) {
    return ((u64)flt2ord(l) << 32) | (unsigned)(~(unsigned)c);
}

// ---- Kernel A1: class-chunked logit scan — 8448 blocks => full occupancy ----
// One thread = one prior x 10 classes. Coalesced loads (stride-1 in n) and
// coalesced [ch][b][n] partial stores. No transcendentals.
__global__ void __launch_bounds__(256) score1_k(
    const float* __restrict__ cls0, const float* __restrict__ cls1, const float* __restrict__ cls2,
    u64* __restrict__ partP, float* __restrict__ partS, int* __restrict__ cnts_mb)
{
    int b = blockIdx.z, ch = blockIdx.y;
    if (blockIdx.x == 0 && ch == 0 && threadIdx.x == 0) {
        cnts_mb[b * CPAD] = 0;                  // cnts[b]
        cnts_mb[(NB + b) * CPAD] = 0;           // maxbits[b]
    }
    int n = blockIdx.x * 256 + threadIdx.x;
    if (n >= NPRIOR) return;
    int W, s, loc; level_of(n, W, s, loc);
    const float* cls = (s == 8) ? cls0 : (s == 16) ? cls1 : cls2;
    int hw = W * W;
    int y = loc / W, x = loc - y * W;
    const float* cp = cls + (size_t)b * NCLS * hw + (size_t)(ch * CPC) * hw + y * W + x;

    float buf[CPC];
#pragma unroll
    for (int k = 0; k < CPC; ++k) buf[k] = cp[(size_t)k * hw];   // 10 indep loads
    float M = buf[0], S2 = -3.4e38f;
    int I = ch * CPC;
#pragma unroll
    for (int k = 1; k < CPC; ++k) {
        float l = buf[k];
        if (l > M) { S2 = M; M = l; I = ch * CPC + k; }
        else       { S2 = fmaxf(S2, l); }
    }
    size_t o = ((size_t)ch * NB + b) * NPRIOR + n;
    partP[o] = packlc(M, I);
    partS[o] = S2;
}

// ---- Kernel A2: streaming merge (coalesced) + sigmoid fast-path + compaction ----
__global__ void __launch_bounds__(256) score2_k(
    const float* __restrict__ cls0, const float* __restrict__ cls1, const float* __restrict__ cls2,
    const float* __restrict__ ob0, const float* __restrict__ ob1, const float* __restrict__ ob2,
    const u64* __restrict__ partP, const float* __restrict__ partS,
    float* __restrict__ sc, int* __restrict__ labels,
    u64* __restrict__ keys, int* __restrict__ cnts, int* __restrict__ rankbuf)
{
#pragma clang fp contract(off)
    int b = blockIdx.y;
    int n = blockIdx.x * 256 + threadIdx.x;
    if (n >= NPRIOR) return;                     // partial last wave: exec-masked
    int W, s, loc; level_of(n, W, s, loc);
    const float* cls = (s == 8) ? cls0 : (s == 16) ? cls1 : cls2;
    const float* ob  = (s == 8) ? ob0  : (s == 16) ? ob1  : ob2;
    int hw = W * W;
    int y = loc / W, x = loc - y * W;

    // streaming merge: best pack, its in-chunk runner-up, max of other chunks.
    size_t idx = (size_t)b * NPRIOR + n;
    const size_t cstride = (size_t)NB * NPRIOR;
    u64 bp = partP[idx];
    float bz = partS[idx];
    float m2 = -3.4e38f;
#pragma unroll
    for (int ch = 1; ch < PCH; ++ch) {
        u64 t = partP[(size_t)ch * cstride + idx];    // coalesced across threads
        float z = partS[(size_t)ch * cstride + idx];
        if (t > bp) { m2 = fmaxf(m2, ord2flt((unsigned)(bp >> 32))); bp = t; bz = z; }
        else        { m2 = fmaxf(m2, ord2flt((unsigned)(t >> 32))); }
    }
    m2 = fmaxf(m2, bz);

    float M = ord2flt((unsigned)(bp >> 32));
    int lab = (int)(~(unsigned)(bp & 0xffffffffull));
    float tM = sigm_np(M);
    // sigmoid order provably follows logit order when
    // gap * e^{-max|logit|} > 1.6e-5 (deriv >= e^{-|x|}/4; err < 1e-6, 4x margin)
    float gap = M - m2;
    float mx = fmaxf(fabsf(M), fabsf(m2));
    if (!((gap * exp_np(-mx)) > 1.6e-5f)) {      // rare exact fallback
        const float* cp = cls + (size_t)b * NCLS * hw + y * W + x;
        tM = -1.0f; lab = 0;
        for (int c = 0; c < NCLS; ++c) {
            float t = sigm_np(cp[(size_t)c * hw]);
            if (t > tM) { tM = t; lab = c; }
        }
    }
    float sObj = sigm_np(ob[(size_t)b * hw + y * W + x]);
    float score = tM * sObj;
    float scv = (score >= 0.65f) ? score : 0.0f;
    sc[idx] = scv;
    labels[idx] = lab;

    // wave-aggregated compaction (order-free; ranking restores stable order)
    int lane = threadIdx.x & 63;
    bool val = scv > 0.0f;
    u64 mb = __ballot(val);
    if (mb) {                                    // wave-uniform branch
        int lead = (int)__builtin_ctzll(mb);
        int base = 0;
        if (lane == lead) base = atomicAdd(&cnts[b * CPAD], (int)__popcll(mb));
        base = __shfl(base, lead);
        if (val) {
            int pos = base + (int)__popcll(mb & ((1ull << lane) - 1ull));
            keys[(size_t)b * CAP + pos] =
                ((u64)__float_as_uint(scv) << 32) | (unsigned)(~(unsigned)n);
            rankbuf[(size_t)b * CAP + pos] = 0;  // no memset needed
        }
    }
}

// ---- Kernel B1: 2D-tiled all-pairs partial rank (atomicAdd accumulate) ----
__global__ void __launch_bounds__(256) rank_part(
    const u64* __restrict__ keys, const int* __restrict__ cnts,
    int* __restrict__ rankbuf)
{
    int b = blockIdx.y, tid = threadIdx.x;
    int cn = min(cnts[b * CPAD], CAP);
    int nt = (cn + 255) >> 8;
    int ntt = nt * nt;
    const u64* keyimg = keys + (size_t)b * CAP;
    int lane = tid & 63;

    for (int t = blockIdx.x; t < ntt; t += gridDim.x) {
        int it = t / nt, jt = t - it * nt;
        int i = it * 256 + tid;
        u64 ki = (i < cn) ? keyimg[i] : ~0ull;
        int rank = 0;
        int jbase = jt * 256;
        int jend = min(jbase + 256, cn);
        for (int jb = jbase; jb < jend; jb += 64) {
            int j = jb + lane;
            u64 kv = (j < cn) ? keyimg[j] : 0ull;
            unsigned lo = (unsigned)kv, hi = (unsigned)(kv >> 32);
            int lim = jend - jb;
#pragma unroll
            for (int l = 0; l < 64; ++l) {
                unsigned jlo = __builtin_amdgcn_readlane(lo, l);
                unsigned jhi = __builtin_amdgcn_readlane(hi, l);
                u64 kj = ((u64)jhi << 32) | jlo;
                rank += (l < lim && kj > ki) ? 1 : 0;
            }
        }
        if (i < cn && rank > 0) atomicAdd(&rankbuf[(size_t)b * CAP + i], rank);
    }
}

// ---- Kernel B2: scatter by rank + decode + housekeeping ----
__global__ void __launch_bounds__(256) scatter_k(
    const u64* __restrict__ keys, const int* __restrict__ cnts,
    const int* __restrict__ rankbuf,
    const float* __restrict__ sc, const int* __restrict__ labels,
    const float* __restrict__ bb0, const float* __restrict__ bb1, const float* __restrict__ bb2,
    float4* __restrict__ sel_box, float* __restrict__ sel_score,
    int* __restrict__ sel_label, int* __restrict__ maxbits, u64* __restrict__ vmask)
{
#pragma clang fp contract(off)
    __shared__ float redbuf[256];
    int b = blockIdx.y, chunk = blockIdx.x, tid = threadIdx.x;
    int cn = min(cnts[b * CPAD], CAP);
    int base = chunk * 256;
    if (chunk != 0 && base >= cn) return;   // housekeeping lives in chunk 0

    const u64* keyimg = keys + (size_t)b * CAP;
    const int* labb = labels + (size_t)b * NPRIOR;
    const float* scb = sc + (size_t)b * NPRIOR;

    int i = base + tid;
    float lmax = 0.0f;
    if (i < cn) {
        int rank = rankbuf[(size_t)b * CAP + i];
        if (rank < KTOP) {
            u64 ki = keyimg[i];
            unsigned n = ~(unsigned)(ki & 0xffffffffull);
            float s = __uint_as_float((unsigned)(ki >> 32));
            float4 bx = decode32(b, (int)n, bb0, bb1, bb2);
            sel_box[(size_t)b * 1024 + rank] = bx;
            sel_score[(size_t)b * 1024 + rank] = s;
            sel_label[(size_t)b * 1024 + rank] = labb[n];
            lmax = fmaxf(fmaxf(fabsf(bx.x), fabsf(bx.y)),
                         fmaxf(fabsf(bx.z), fabsf(bx.w)));
        }
    }

    if (chunk == 0) {
        if (cn < KTOP && tid == 0) {   // rare fill path
            float lm = 0.0f;
            int r = cn;
            for (int n = 0; n < NPRIOR && r < KTOP; ++n) {
                if (scb[n] == 0.0f) {
                    float4 bx = decode32(b, n, bb0, bb1, bb2);
                    sel_box[(size_t)b * 1024 + r] = bx;
                    sel_score[(size_t)b * 1024 + r] = 0.0f;
                    sel_label[(size_t)b * 1024 + r] = labb[n];
                    lm = fmaxf(lm, fmaxf(fmaxf(fabsf(bx.x), fabsf(bx.y)),
                                         fmaxf(fabsf(bx.z), fabsf(bx.w))));
                    ++r;
                }
            }
            lmax = fmaxf(lmax, lm);
        }
        if (tid < 24) {   // padding rows 1000..1023
            sel_box[(size_t)b * 1024 + 1000 + tid] = make_float4(0.f, 0.f, 0.f, 0.f);
            sel_score[(size_t)b * 1024 + 1000 + tid] = 0.0f;
            sel_label[(size_t)b * 1024 + 1000 + tid] = 0;
        }
        if (tid < 16) {   // vmask closed form
            int vc = min(cn, KTOP);
            int lo = tid * 64;
            u64 m;
            if (vc >= lo + 64)      m = ~0ull;
            else if (vc <= lo)      m = 0ull;
            else                    m = (1ull << (vc - lo)) - 1ull;
            vmask[b * 16 + tid] = m;
        }
    }

    redbuf[tid] = lmax;
    __syncthreads();
    for (int off = 128; off > 0; off >>= 1) {
        if (tid < off) redbuf[tid] = fmaxf(redbuf[tid], redbuf[tid + off]);
        __syncthreads();
    }
    if (tid == 0) atomicMax(&maxbits[b * CPAD], __float_as_int(redbuf[0]));
}

// ---- Kernel C: ballot-free suppression bitmask, per-lane column ownership ----
__global__ void __launch_bounds__(256) build_mask_T(
    const float4* __restrict__ sel_box, const int* __restrict__ sel_label,
    const int* __restrict__ maxbits, u64* __restrict__ Cmask)
{
#pragma clang fp contract(off)
    __shared__ float4 obr[256];
    __shared__ float arr[256];
    int b = blockIdx.y;
    int cg = blockIdx.x & 15, rgq = blockIdx.x >> 4;
    if (rgq * 4 > cg) return;
    int tid = threadIdx.x, wave = tid >> 6, lane = tid & 63;
    float mc = __int_as_float(maxbits[b * CPAD]) + 1.0f;

    {
        int row = rgq * 256 + tid;
        float4 v = sel_box[(size_t)b * 1024 + row];
        float off = (float)sel_label[(size_t)b * 1024 + row] * mc;
        v.x += off; v.y += off; v.z += off; v.w += off;
        obr[tid] = v;
        arr[tid] = (v.z - v.x) * (v.w - v.y);
    }
    int col = cg * 64 + lane;
    float4 a = sel_box[(size_t)b * 1024 + col];
    float offc = (float)sel_label[(size_t)b * 1024 + col] * mc;
    a.x += offc; a.y += offc; a.z += offc; a.w += offc;
    float ac = (a.z - a.x) * (a.w - a.y);
    __syncthreads();

    int rg = rgq * 4 + wave;
    if (rg > cg) return;
    u64 bits = 0;
    int rowbase = rg * 64;
#pragma unroll 8
    for (int r = 0; r < 64; ++r) {
        int row = rowbase + r;
        float4 rb = obr[wave * 64 + r];
        float ra = arr[wave * 64 + r];
        bool pred = false;
        if (row < col && row < KTOP && col < KTOP) {
            float tlx = fmaxf(rb.x, a.x), tly = fmaxf(rb.y, a.y);
            float brx = fminf(rb.z, a.z), bry = fminf(rb.w, a.w);
            float w = fmaxf(brx - tlx, 0.0f), h = fmaxf(bry - tly, 0.0f);
            float inter = w * h;
            float uni = (ra + ac) - inter;
            float iou = inter / (uni + 1e-6f);
            pred = iou > 0.65f;
        }
        bits |= pred ? (1ull << r) : 0ull;
    }
    Cmask[((size_t)b * 16 + rg) * 1024 + col] = bits;
}

// ---- Kernel D: ballot-fixpoint greedy NMS + output ----
__global__ void __launch_bounds__(64) nms_fixpoint_write(
    const u64* __restrict__ Cmask, const u64* __restrict__ vmask,
    const float4* __restrict__ sel_box, const float* __restrict__ sel_score,
    const int* __restrict__ sel_label, float* __restrict__ out)
{
    int b = blockIdx.x, lane = threadIdx.x;
    const u64* Cimg = Cmask + (size_t)b * 16 * 1024;
    u64 Khist[16];
#pragma unroll
    for (int g = 0; g < 16; ++g) {
        int col = g * 64 + lane;
        bool supp = false;
#pragma unroll
        for (int gp = 0; gp < g; ++gp)
            supp |= (Cimg[(size_t)gp * 1024 + col] & Khist[gp]) != 0ull;
        u64 V = vmask[b * 16 + g] & ~__ballot(supp);
        u64 T = Cimg[(size_t)g * 1024 + col];
        u64 K = V;
        for (int it = 0; it < 64; ++it) {
            u64 Knew = V & ~__ballot((T & K) != 0ull);
            if (Knew == K) break;
            K = Knew;
        }
        Khist[g] = K;
    }

    const size_t selo = (size_t)b * 1024;
    float* lab_o = out + (size_t)NB * KTOP * 5;
    float* keep_o = lab_o + (size_t)NB * KTOP;
#pragma unroll
    for (int g = 0; g < 16; ++g) {
        int k = g * 64 + lane;
        if (k >= KTOP) break;
        bool fin = (Khist[g] >> lane) & 1ull;
        float4 bx = sel_box[selo + k];
        float s = sel_score[selo + k];
        int lb = sel_label[selo + k];
        size_t o5 = ((size_t)b * KTOP + k) * 5;
        out[o5 + 0] = fin ? bx.x : 0.0f;
        out[o5 + 1] = fin ? bx.y : 0.0f;
        out[o5 + 2] = fin ? bx.z : 0.0f;
        out[o5 + 3] = fin ? bx.w : 0.0f;
        out[o5 + 4] = fin ? s : 0.0f;
        lab_o[b * KTOP + k] = fin ? (float)lb : -1.0f;
        keep_o[b * KTOP + k] = fin ? 1.0f : 0.0f;
    }
}

extern "C" void kernel_launch(void* const* d_in, const int* in_sizes, int n_in,
                              void* d_out, int out_size, void* d_ws, size_t ws_size,
                              hipStream_t stream) {
    const float* cls0 = (const float*)d_in[0];
    const float* cls1 = (const float*)d_in[1];
    const float* cls2 = (const float*)d_in[2];
    const float* bb0  = (const float*)d_in[3];
    const float* bb1  = (const float*)d_in[4];
    const float* bb2  = (const float*)d_in[5];
    const float* ob0  = (const float*)d_in[6];
    const float* ob1  = (const float*)d_in[7];
    const float* ob2  = (const float*)d_in[8];
    float* out = (float*)d_out;

    char* w = (char*)d_ws;
    size_t used = 0;
    auto alloc = [&](size_t bytes) -> void* {
        void* p = (void*)(w + used);
        used += (bytes + 255) & ~(size_t)255;
        return p;
    };
    float* sc        = (float*)alloc((size_t)NB * NPRIOR * 4);
    int* labels      = (int*)alloc((size_t)NB * NPRIOR * 4);
    u64* partP       = (u64*)alloc((size_t)PCH * NB * NPRIOR * 8);
    float* partS     = (float*)alloc((size_t)PCH * NB * NPRIOR * 4);
    u64* keys        = (u64*)alloc((size_t)NB * CAP * 8);
    int* cnts_mb     = (int*)alloc((size_t)2 * NB * CPAD * 4);   // cnts | maxbits
    int* rankbuf     = (int*)alloc((size_t)NB * CAP * 4);
    float4* sel_box  = (float4*)alloc((size_t)NB * 1024 * 16);
    float* sel_score = (float*)alloc((size_t)NB * 1024 * 4);
    int* sel_label   = (int*)alloc((size_t)NB * 1024 * 4);
    u64* vmask       = (u64*)alloc((size_t)NB * 16 * 8);
    u64* Cmask       = (u64*)alloc((size_t)NB * 16 * 1024 * 8);

    if (used > ws_size) return;   // OOB-write guard

    int* cnts = cnts_mb;
    int* maxbits = cnts_mb + NB * CPAD;

    score1_k<<<dim3((NPRIOR + 255) / 256, PCH, NB), 256, 0, stream>>>(
        cls0, cls1, cls2, partP, partS, cnts_mb);
    score2_k<<<dim3((NPRIOR + 255) / 256, NB), 256, 0, stream>>>(
        cls0, cls1, cls2, ob0, ob1, ob2, partP, partS,
        sc, labels, keys, cnts, rankbuf);
    rank_part<<<dim3(64, NB), 256, 0, stream>>>(keys, cnts, rankbuf);
    scatter_k<<<dim3((CAP + 255) / 256, NB), 256, 0, stream>>>(
        keys, cnts, rankbuf, sc, labels, bb0, bb1, bb2,
        sel_box, sel_score, sel_label, maxbits, vmask);
    build_mask_T<<<dim3(64, NB), 256, 0, stream>>>(sel_box, sel_label, maxbits, Cmask);
    nms_fixpoint_write<<<NB, 64, 0, stream>>>(
        Cmask, vmask, sel_box, sel_score, sel_label, out);
}

// Round 19
// 117.447 us; speedup vs baseline: 1.0815x; 1.0815x over previous
//
#include <hip/hip_runtime.h>
#include <stdint.h>

#define NPRIOR 8400
#define NB 32
#define NCLS 80
#define KTOP 1000
#define CAP 8400   // worst-case candidates
#define CPAD 16    // ints per counter slot (64B)

typedef unsigned long long u64;

// Bit-exact replica of numpy's float32 SIMD exp (Cephes-style, FMA path).
__device__ __forceinline__ float exp_np(float x) {
#pragma clang fp contract(off)
    if (x > 88.72283935546875f) return __builtin_huge_valf();
    if (x < -87.3365478515625f) return 0.0f;
    float q = rintf(x * 1.442695040f);
    float r = fmaf(q, -6.93145752e-1f, x);
    r = fmaf(q, -1.42860677e-6f, r);
    float p = fmaf(1.9875691500e-4f, r, 1.3981999507e-3f);
    p = fmaf(p, r, 8.3334519073e-3f);
    p = fmaf(p, r, 4.1665795894e-2f);
    p = fmaf(p, r, 1.6666665459e-1f);
    p = fmaf(p, r, 5.0000001201e-1f);
    float r2 = r * r;
    p = fmaf(p, r2, r);
    p = p + 1.0f;
    return ldexpf(p, (int)q);
}
__device__ __forceinline__ float sigm_np(float x) {
#pragma clang fp contract(off)
    float t = exp_np(-x);
    return 1.0f / (1.0f + t);
}

__device__ __forceinline__ void level_of(int n, int& W, int& s, int& loc) {
    if (n < 6400)      { W = 80; s = 8;  loc = n; }
    else if (n < 8000) { W = 40; s = 16; loc = n - 6400; }
    else               { W = 20; s = 32; loc = n - 8000; }
}

__device__ float4 decode32(int b, int n,
                           const float* bb0, const float* bb1, const float* bb2) {
#pragma clang fp contract(off)
    int W, s, loc; level_of(n, W, s, loc);
    const float* bb = (s == 8) ? bb0 : (s == 16) ? bb1 : bb2;
    int hw = W * W;
    int y = loc / W, x = loc - y * W;
    const float* bp = bb + (size_t)b * 4 * hw + y * W + x;
    float fs = (float)s;
    float cx = (float)x * fs, cy = (float)y * fs;
    float xc = bp[0] * fs + cx;
    float yc = bp[hw] * fs + cy;
    float wv = exp_np(bp[2 * hw]) * fs;
    float hv = exp_np(bp[3 * hw]) * fs;
    float wv2 = wv * 0.5f, hv2 = hv * 0.5f;
    float4 r;
    r.x = xc - wv2;
    r.y = yc - hv2;
    r.z = xc + wv2;
    r.w = yc + hv2;
    return r;
}

__device__ __forceinline__ unsigned flt2ord(float f) {
    unsigned u = __float_as_uint(f);
    return u ^ ((u >> 31) ? 0xffffffffu : 0x80000000u);
}
__device__ __forceinline__ float ord2flt(unsigned u) {
    u ^= ((u >> 31) ? 0x80000000u : 0xffffffffu);
    return __uint_as_float(u);
}
__device__ __forceinline__ u64 packlc(float l, int c) {
    return ((u64)flt2ord(l) << 32) | (unsigned)(~(unsigned)c);
}

// ---- init: zero padded counters (cnts | maxbits) ----
__global__ void __launch_bounds__(64) init_k(int* __restrict__ cnts_mb) {
    cnts_mb[threadIdx.x * CPAD] = 0;   // t<32: cnts[b]; t>=32: maxbits[b-32]
}

// ---- Kernel A (fused, in-wave chunk parallel): 4 lanes/prior x 20 classes ----
// lane>>4 = chunk, lane&15 + wave*16 = prior-in-block. Merge (pack,S2) via
// shfl_xor(16),shfl_xor(32) — exact streaming-merge semantics (r15-verified).
// No partials, no LDS. 4224 blocks => deep wave issue pool.
__global__ void __launch_bounds__(256) score_k(
    const float* __restrict__ cls0, const float* __restrict__ cls1, const float* __restrict__ cls2,
    const float* __restrict__ ob0,  const float* __restrict__ ob1,  const float* __restrict__ ob2,
    float* __restrict__ sc, int* __restrict__ labels,
    u64* __restrict__ keys, int* __restrict__ cnts, int* __restrict__ rankbuf)
{
#pragma clang fp contract(off)
    int b = blockIdx.y;
    int tid = threadIdx.x, wv = tid >> 6, l = tid & 63;
    int cid = l >> 4;                            // class chunk 0..3
    int n = blockIdx.x * 64 + wv * 16 + (l & 15);
    bool nvalid = (n < NPRIOR);
    int nc = nvalid ? n : NPRIOR - 1;            // clamp for safe addresses
    int W, s, loc; level_of(nc, W, s, loc);
    const float* cls = (s == 8) ? cls0 : (s == 16) ? cls1 : cls2;
    const float* ob  = (s == 8) ? ob0  : (s == 16) ? ob1  : ob2;
    int hw = W * W;
    int y = loc / W, x = loc - y * W;
    const float* cp = cls + (size_t)b * NCLS * hw + y * W + x;
    int c0 = cid * 20;

    // 20 independent loads, fully unrolled -> deep MLP
    float buf[20];
#pragma unroll
    for (int k = 0; k < 20; ++k) buf[k] = cp[(size_t)(c0 + k) * hw];
    float M = buf[0], S2 = -3.4e38f;
    int I = c0;
#pragma unroll
    for (int k = 1; k < 20; ++k) {
        float lg = buf[k];
        if (lg > M) { S2 = M; M = lg; I = c0 + k; }
        else        { S2 = fmaxf(S2, lg); }
    }
    u64 p = packlc(M, I);
    float s2 = S2;
    // merge the 4 chunk lanes (same prior): xor 16, then 32
#pragma unroll
    for (int mk = 16; mk <= 32; mk <<= 1) {
        u64 po = __shfl_xor(p, mk, 64);
        float so = __shfl_xor(s2, mk, 64);
        if (po > p) { s2 = fmaxf(so, ord2flt((unsigned)(p >> 32))); p = po; }
        else        { s2 = fmaxf(s2, ord2flt((unsigned)(po >> 32))); }
    }

    float Mg = ord2flt((unsigned)(p >> 32));
    int lab = (int)(~(unsigned)(p & 0xffffffffull)) & 0xff;
    float tM = sigm_np(Mg);
    // sigmoid order provably follows logit order when
    // gap * e^{-max|logit|} > 1.6e-5 (deriv >= e^{-|x|}/4; err < 1e-6, 4x margin)
    float gap = Mg - s2;
    float mx = fmaxf(fabsf(Mg), fabsf(s2));
    bool need = !((gap * exp_np(-mx)) > 1.6e-5f) && nvalid;
    if (__ballot(need)) {                        // wave-parallel exact fallback
        u64 pk = 0;
#pragma unroll
        for (int k = 0; k < 20; ++k) {
            float t = sigm_np(cp[(size_t)(c0 + k) * hw]);   // L1/L2-hot reload
            u64 q = ((u64)flt2ord(t) << 32) | (unsigned)(~(unsigned)(c0 + k));
            pk = (q > pk) ? q : pk;
        }
#pragma unroll
        for (int mk = 16; mk <= 32; mk <<= 1) {
            u64 qo = __shfl_xor(pk, mk, 64);
            pk = (qo > pk) ? qo : pk;
        }
        if (need) {
            tM = ord2flt((unsigned)(pk >> 32));
            lab = (int)(~(unsigned)(pk & 0xffffffffull)) & 0xff;
        }
    }

    bool owner = (cid == 0) && nvalid;
    float scv = 0.0f;
    if (owner) {
        float sObj = sigm_np(ob[(size_t)b * hw + y * W + x]);
        float score = tM * sObj;
        scv = (score >= 0.65f) ? score : 0.0f;
        sc[(size_t)b * NPRIOR + n] = scv;
        labels[(size_t)b * NPRIOR + n] = lab;
    }

    // wave-aggregated compaction (order-free; ranking restores stable order)
    bool val = owner && (scv > 0.0f);
    u64 mb = __ballot(val);
    if (mb) {                                    // wave-uniform branch
        int lead = (int)__builtin_ctzll(mb);
        int base = 0;
        if (l == lead) base = atomicAdd(&cnts[b * CPAD], (int)__popcll(mb));
        base = __shfl(base, lead);
        if (val) {
            int pos = base + (int)__popcll(mb & ((1ull << l) - 1ull));
            keys[(size_t)b * CAP + pos] =
                ((u64)__float_as_uint(scv) << 32) | (unsigned)(~(unsigned)n);
            rankbuf[(size_t)b * CAP + pos] = 0;  // no memset needed
        }
    }
}

// ---- Kernel B1: 2D-tiled all-pairs partial rank (atomicAdd accumulate) ----
__global__ void __launch_bounds__(256) rank_part(
    const u64* __restrict__ keys, const int* __restrict__ cnts,
    int* __restrict__ rankbuf)
{
    int b = blockIdx.y, tid = threadIdx.x;
    int cn = min(cnts[b * CPAD], CAP);
    int nt = (cn + 255) >> 8;
    int ntt = nt * nt;
    const u64* keyimg = keys + (size_t)b * CAP;
    int lane = tid & 63;

    for (int t = blockIdx.x; t < ntt; t += gridDim.x) {
        int it = t / nt, jt = t - it * nt;
        int i = it * 256 + tid;
        u64 ki = (i < cn) ? keyimg[i] : ~0ull;
        int rank = 0;
        int jbase = jt * 256;
        int jend = min(jbase + 256, cn);
        for (int jb = jbase; jb < jend; jb += 64) {
            int j = jb + lane;
            u64 kv = (j < cn) ? keyimg[j] : 0ull;
            unsigned lo = (unsigned)kv, hi = (unsigned)(kv >> 32);
            int lim = jend - jb;
#pragma unroll
            for (int l = 0; l < 64; ++l) {
                unsigned jlo = __builtin_amdgcn_readlane(lo, l);
                unsigned jhi = __builtin_amdgcn_readlane(hi, l);
                u64 kj = ((u64)jhi << 32) | jlo;
                rank += (l < lim && kj > ki) ? 1 : 0;
            }
        }
        if (i < cn && rank > 0) atomicAdd(&rankbuf[(size_t)b * CAP + i], rank);
    }
}

// ---- Kernel B2: scatter by rank + decode + housekeeping ----
__global__ void __launch_bounds__(256) scatter_k(
    const u64* __restrict__ keys, const int* __restrict__ cnts,
    const int* __restrict__ rankbuf,
    const float* __restrict__ sc, const int* __restrict__ labels,
    const float* __restrict__ bb0, const float* __restrict__ bb1, const float* __restrict__ bb2,
    float4* __restrict__ sel_box, float* __restrict__ sel_score,
    int* __restrict__ sel_label, int* __restrict__ maxbits, u64* __restrict__ vmask)
{
#pragma clang fp contract(off)
    __shared__ float redbuf[256];
    int b = blockIdx.y, chunk = blockIdx.x, tid = threadIdx.x;
    int cn = min(cnts[b * CPAD], CAP);
    int base = chunk * 256;
    if (chunk != 0 && base >= cn) return;   // housekeeping lives in chunk 0

    const u64* keyimg = keys + (size_t)b * CAP;
    const int* labb = labels + (size_t)b * NPRIOR;
    const float* scb = sc + (size_t)b * NPRIOR;

    int i = base + tid;
    float lmax = 0.0f;
    if (i < cn) {
        int rank = rankbuf[(size_t)b * CAP + i];
        if (rank < KTOP) {
            u64 ki = keyimg[i];
            unsigned n = ~(unsigned)(ki & 0xffffffffull);
            float s = __uint_as_float((unsigned)(ki >> 32));
            float4 bx = decode32(b, (int)n, bb0, bb1, bb2);
            sel_box[(size_t)b * 1024 + rank] = bx;
            sel_score[(size_t)b * 1024 + rank] = s;
            sel_label[(size_t)b * 1024 + rank] = labb[n];
            lmax = fmaxf(fmaxf(fabsf(bx.x), fabsf(bx.y)),
                         fmaxf(fabsf(bx.z), fabsf(bx.w)));
        }
    }

    if (chunk == 0) {
        if (cn < KTOP && tid == 0) {   // rare fill path
            float lm = 0.0f;
            int r = cn;
            for (int n = 0; n < NPRIOR && r < KTOP; ++n) {
                if (scb[n] == 0.0f) {
                    float4 bx = decode32(b, n, bb0, bb1, bb2);
                    sel_box[(size_t)b * 1024 + r] = bx;
                    sel_score[(size_t)b * 1024 + r] = 0.0f;
                    sel_label[(size_t)b * 1024 + r] = labb[n];
                    lm = fmaxf(lm, fmaxf(fmaxf(fabsf(bx.x), fabsf(bx.y)),
                                         fmaxf(fabsf(bx.z), fabsf(bx.w))));
                    ++r;
                }
            }
            lmax = fmaxf(lmax, lm);
        }
        if (tid < 24) {   // padding rows 1000..1023
            sel_box[(size_t)b * 1024 + 1000 + tid] = make_float4(0.f, 0.f, 0.f, 0.f);
            sel_score[(size_t)b * 1024 + 1000 + tid] = 0.0f;
            sel_label[(size_t)b * 1024 + 1000 + tid] = 0;
        }
        if (tid < 16) {   // vmask closed form
            int vc = min(cn, KTOP);
            int lo = tid * 64;
            u64 m;
            if (vc >= lo + 64)      m = ~0ull;
            else if (vc <= lo)      m = 0ull;
            else                    m = (1ull << (vc - lo)) - 1ull;
            vmask[b * 16 + tid] = m;
        }
    }

    redbuf[tid] = lmax;
    __syncthreads();
    for (int off = 128; off > 0; off >>= 1) {
        if (tid < off) redbuf[tid] = fmaxf(redbuf[tid], redbuf[tid + off]);
        __syncthreads();
    }
    if (tid == 0) atomicMax(&maxbits[b * CPAD], __float_as_int(redbuf[0]));
}

// ---- Kernel C: ballot-free suppression bitmask, per-lane column ownership ----
__global__ void __launch_bounds__(256) build_mask_T(
    const float4* __restrict__ sel_box, const int* __restrict__ sel_label,
    const int* __restrict__ maxbits, u64* __restrict__ Cmask)
{
#pragma clang fp contract(off)
    __shared__ float4 obr[256];
    __shared__ float arr[256];
    int b = blockIdx.y;
    int cg = blockIdx.x & 15, rgq = blockIdx.x >> 4;
    if (rgq * 4 > cg) return;
    int tid = threadIdx.x, wave = tid >> 6, lane = tid & 63;
    float mc = __int_as_float(maxbits[b * CPAD]) + 1.0f;

    {
        int row = rgq * 256 + tid;
        float4 v = sel_box[(size_t)b * 1024 + row];
        float off = (float)sel_label[(size_t)b * 1024 + row] * mc;
        v.x += off; v.y += off; v.z += off; v.w += off;
        obr[tid] = v;
        arr[tid] = (v.z - v.x) * (v.w - v.y);
    }
    int col = cg * 64 + lane;
    float4 a = sel_box[(size_t)b * 1024 + col];
    float offc = (float)sel_label[(size_t)b * 1024 + col] * mc;
    a.x += offc; a.y += offc; a.z += offc; a.w += offc;
    float ac = (a.z - a.x) * (a.w - a.y);
    __syncthreads();

    int rg = rgq * 4 + wave;
    if (rg > cg) return;
    u64 bits = 0;
    int rowbase = rg * 64;
#pragma unroll 8
    for (int r = 0; r < 64; ++r) {
        int row = rowbase + r;
        float4 rb = obr[wave * 64 + r];
        float ra = arr[wave * 64 + r];
        bool pred = false;
        if (row < col && row < KTOP && col < KTOP) {
            float tlx = fmaxf(rb.x, a.x), tly = fmaxf(rb.y, a.y);
            float brx = fminf(rb.z, a.z), bry = fminf(rb.w, a.w);
            float w = fmaxf(brx - tlx, 0.0f), h = fmaxf(bry - tly, 0.0f);
            float inter = w * h;
            float uni = (ra + ac) - inter;
            float iou = inter / (uni + 1e-6f);
            pred = iou > 0.65f;
        }
        bits |= pred ? (1ull << r) : 0ull;
    }
    Cmask[((size_t)b * 16 + rg) * 1024 + col] = bits;
}

// ---- Kernel D: ballot-fixpoint greedy NMS + output ----
__global__ void __launch_bounds__(64) nms_fixpoint_write(
    const u64* __restrict__ Cmask, const u64* __restrict__ vmask,
    const float4* __restrict__ sel_box, const float* __restrict__ sel_score,
    const int* __restrict__ sel_label, float* __restrict__ out)
{
    int b = blockIdx.x, lane = threadIdx.x;
    const u64* Cimg = Cmask + (size_t)b * 16 * 1024;
    u64 Khist[16];
#pragma unroll
    for (int g = 0; g < 16; ++g) {
        int col = g * 64 + lane;
        bool supp = false;
#pragma unroll
        for (int gp = 0; gp < g; ++gp)
            supp |= (Cimg[(size_t)gp * 1024 + col] & Khist[gp]) != 0ull;
        u64 V = vmask[b * 16 + g] & ~__ballot(supp);
        u64 T = Cimg[(size_t)g * 1024 + col];
        u64 K = V;
        for (int it = 0; it < 64; ++it) {
            u64 Knew = V & ~__ballot((T & K) != 0ull);
            if (Knew == K) break;
            K = Knew;
        }
        Khist[g] = K;
    }

    const size_t selo = (size_t)b * 1024;
    float* lab_o = out + (size_t)NB * KTOP * 5;
    float* keep_o = lab_o + (size_t)NB * KTOP;
#pragma unroll
    for (int g = 0; g < 16; ++g) {
        int k = g * 64 + lane;
        if (k >= KTOP) break;
        bool fin = (Khist[g] >> lane) & 1ull;
        float4 bx = sel_box[selo + k];
        float s = sel_score[selo + k];
        int lb = sel_label[selo + k];
        size_t o5 = ((size_t)b * KTOP + k) * 5;
        out[o5 + 0] = fin ? bx.x : 0.0f;
        out[o5 + 1] = fin ? bx.y : 0.0f;
        out[o5 + 2] = fin ? bx.z : 0.0f;
        out[o5 + 3] = fin ? bx.w : 0.0f;
        out[o5 + 4] = fin ? s : 0.0f;
        lab_o[b * KTOP + k] = fin ? (float)lb : -1.0f;
        keep_o[b * KTOP + k] = fin ? 1.0f : 0.0f;
    }
}

extern "C" void kernel_launch(void* const* d_in, const int* in_sizes, int n_in,
                              void* d_out, int out_size, void* d_ws, size_t ws_size,
                              hipStream_t stream) {
    const float* cls0 = (const float*)d_in[0];
    const float* cls1 = (const float*)d_in[1];
    const float* cls2 = (const float*)d_in[2];
    const float* bb0  = (const float*)d_in[3];
    const float* bb1  = (const float*)d_in[4];
    const float* bb2  = (const float*)d_in[5];
    const float* ob0  = (const float*)d_in[6];
    const float* ob1  = (const float*)d_in[7];
    const float* ob2  = (const float*)d_in[8];
    float* out = (float*)d_out;

    char* w = (char*)d_ws;
    size_t used = 0;
    auto alloc = [&](size_t bytes) -> void* {
        void* p = (void*)(w + used);
        used += (bytes + 255) & ~(size_t)255;
        return p;
    };
    float* sc        = (float*)alloc((size_t)NB * NPRIOR * 4);
    int* labels      = (int*)alloc((size_t)NB * NPRIOR * 4);
    u64* keys        = (u64*)alloc((size_t)NB * CAP * 8);
    int* cnts_mb     = (int*)alloc((size_t)2 * NB * CPAD * 4);   // cnts | maxbits
    int* rankbuf     = (int*)alloc((size_t)NB * CAP * 4);
    float4* sel_box  = (float4*)alloc((size_t)NB * 1024 * 16);
    float* sel_score = (float*)alloc((size_t)NB * 1024 * 4);
    int* sel_label   = (int*)alloc((size_t)NB * 1024 * 4);
    u64* vmask       = (u64*)alloc((size_t)NB * 16 * 8);
    u64* Cmask       = (u64*)alloc((size_t)NB * 16 * 1024 * 8);

    if (used > ws_size) return;   // OOB-write guard

    int* cnts = cnts_mb;
    int* maxbits = cnts_mb + NB * CPAD;

    init_k<<<1, 64, 0, stream>>>(cnts_mb);
    score_k<<<dim3((NPRIOR + 63) / 64, NB), 256, 0, stream>>>(
        cls0, cls1, cls2, ob0, ob1, ob2, sc, labels, keys, cnts, rankbuf);
    rank_part<<<dim3(64, NB), 256, 0, stream>>>(keys, cnts, rankbuf);
    scatter_k<<<dim3((CAP + 255) / 256, NB), 256, 0, stream>>>(
        keys, cnts, rankbuf, sc, labels, bb0, bb1, bb2,
        sel_box, sel_score, sel_label, maxbits, vmask);
    build_mask_T<<<dim3(64, NB), 256, 0, stream>>>(sel_box, sel_label, maxbits, Cmask);
    nms_fixpoint_write<<<NB, 64, 0, stream>>>(
        Cmask, vmask, sel_box, sel_score, sel_label, out);
}